// Round 6
// baseline (50.433 us; speedup 1.0000x reference)
//
#include <hip/hip_runtime.h>

// Welford mean/variance over batch dim.
// x: (B=64, C=64, H=128, W=128) fp32; m0,s0: (C,H,W) fp32; n0: int scalar.
// out: (2, C, H, W) fp32 = [m; s].

#define B_DIM 64
#define CHW (64 * 128 * 128)   // 1,048,576

typedef float f32x4 __attribute__((ext_vector_type(4)));

__global__ __launch_bounds__(256) void welford_kernel(
    const float* __restrict__ x,
    const float* __restrict__ m0,
    const float* __restrict__ s0,
    const int* __restrict__ n0p,
    float* __restrict__ out)
{
    // Each thread owns 4 ADJACENT float4 columns (64 B) -> each wave loads
    // 4 KB contiguous per b-step (R5's 2 KB gave +5%): fewest, widest
    // address streams for HBM page locality; 4 independent Welford chains.
    const int t = blockIdx.x * blockDim.x + threadIdx.x;   // quad index
    const int stride4 = CHW / 4;                           // 262,144 float4 cols
    const int c0 = 4 * t;                                  // first float4 col
    if (c0 >= stride4) return;

    const f32x4* __restrict__ x4 = (const f32x4*)x;
    f32x4 m[4], s[4];
    #pragma unroll
    for (int q = 0; q < 4; ++q) {
        m[q] = ((const f32x4*)m0)[c0 + q];
        s[q] = ((const f32x4*)s0)[c0 + q];
    }
    float n = (float)(*n0p);   // wave-uniform scalar load

    #pragma unroll 2
    for (int b = 0; b < B_DIM; ++b) {
        f32x4 xi[4];
        #pragma unroll
        for (int q = 0; q < 4; ++q) xi[q] = x4[b * stride4 + c0 + q];
        // 1-ulp reciprocal (R5: absmax 0.25 << 2.6 threshold, deterministic).
        float inv = __builtin_amdgcn_rcpf(n + 1.0f);
        #pragma unroll
        for (int q = 0; q < 4; ++q) {
            #pragma unroll
            for (int j = 0; j < 4; ++j) {
                float d = xi[q][j] - m[q][j];
                m[q][j] += d * inv;
                s[q][j] += (xi[q][j] - m[q][j]) * d;
            }
        }
        n += 1.0f;
    }

    f32x4* out4 = (f32x4*)out;
    #pragma unroll
    for (int q = 0; q < 4; ++q) {
        out4[c0 + q]           = m[q];   // mean block
        out4[stride4 + c0 + q] = s[q];   // M2 block
    }
}

extern "C" void kernel_launch(void* const* d_in, const int* in_sizes, int n_in,
                              void* d_out, int out_size, void* d_ws, size_t ws_size,
                              hipStream_t stream) {
    const float* x  = (const float*)d_in[0];
    const float* m0 = (const float*)d_in[1];
    const float* s0 = (const float*)d_in[2];
    const int*   n0 = (const int*)d_in[3];
    float* out = (float*)d_out;

    const int quads = (CHW / 4) / 4;     // 65,536 thread-quads
    const int block = 256;
    const int grid = (quads + block - 1) / block;  // 256 blocks -> 1/CU, 4 waves/CU
    welford_kernel<<<grid, block, 0, stream>>>(x, m0, s0, n0, out);
}

// Round 7
// 45.893 us; speedup vs baseline: 1.0989x; 1.0989x over previous
//
#include <hip/hip_runtime.h>

// Welford mean/variance over batch dim.
// x: (B=64, C=64, H=128, W=128) fp32; m0,s0: (C,H,W) fp32; n0: int scalar.
// out: (2, C, H, W) fp32 = [m; s].
//
// R5 geometry (proven best: 47.0 us, 5.79 TB/s): 2 adjacent float4 per
// thread, 512 blocks -> 2 blocks/CU, 8 waves/CU. Only change vs R5:
// unroll 4 -> 8 (16 loads in flight per wave) as a clean ILP-depth A/B.

#define B_DIM 64
#define CHW (64 * 128 * 128)   // 1,048,576

typedef float f32x4 __attribute__((ext_vector_type(4)));

__global__ __launch_bounds__(256) void welford_kernel(
    const float* __restrict__ x,
    const float* __restrict__ m0,
    const float* __restrict__ s0,
    const int* __restrict__ n0p,
    float* __restrict__ out)
{
    const int t = blockIdx.x * blockDim.x + threadIdx.x;   // pair index
    const int stride4 = CHW / 4;                           // 262,144 float4 cols
    const int c0 = 2 * t;                                  // first float4 col
    if (c0 >= stride4) return;

    const f32x4* __restrict__ x4 = (const f32x4*)x;
    f32x4 ma = ((const f32x4*)m0)[c0];
    f32x4 mb = ((const f32x4*)m0)[c0 + 1];
    f32x4 sa = ((const f32x4*)s0)[c0];
    f32x4 sb = ((const f32x4*)s0)[c0 + 1];
    float n = (float)(*n0p);   // wave-uniform scalar load

    #pragma unroll 8
    for (int b = 0; b < B_DIM; ++b) {
        f32x4 xa = x4[b * stride4 + c0];
        f32x4 xb = x4[b * stride4 + c0 + 1];
        // 1-ulp reciprocal (R5: absmax 0.25 << 2.6 threshold, deterministic).
        float inv = __builtin_amdgcn_rcpf(n + 1.0f);
        #pragma unroll
        for (int j = 0; j < 4; ++j) {
            float da = xa[j] - ma[j];
            ma[j] += da * inv;
            sa[j] += (xa[j] - ma[j]) * da;
            float db = xb[j] - mb[j];
            mb[j] += db * inv;
            sb[j] += (xb[j] - mb[j]) * db;
        }
        n += 1.0f;
    }

    f32x4* out4 = (f32x4*)out;
    out4[c0]               = ma;   // mean block
    out4[c0 + 1]           = mb;
    out4[stride4 + c0]     = sa;   // M2 block
    out4[stride4 + c0 + 1] = sb;

}

extern "C" void kernel_launch(void* const* d_in, const int* in_sizes, int n_in,
                              void* d_out, int out_size, void* d_ws, size_t ws_size,
                              hipStream_t stream) {
    const float* x  = (const float*)d_in[0];
    const float* m0 = (const float*)d_in[1];
    const float* s0 = (const float*)d_in[2];
    const int*   n0 = (const int*)d_in[3];
    float* out = (float*)d_out;

    const int pairs = (CHW / 4) / 2;     // 131,072 thread-pairs
    const int block = 256;
    const int grid = (pairs + block - 1) / block;  // 512 blocks -> 2/CU, 8 waves/CU
    welford_kernel<<<grid, block, 0, stream>>>(x, m0, s0, n0, out);
}